// Round 8
// baseline (49.573 us; speedup 1.0000x reference)
//
#include <hip/hip_runtime.h>

typedef float v4f __attribute__((ext_vector_type(4)));

// 45-tap palindromic filter, padded to 48 with zeros so every phase uses a
// uniform 12-tap loop: out phase p uses weight BASE48[4*j + 3 - p].
constexpr float BASE48[48] = {
    -0.00463495665f, -0.00363442646f, 3.84904063e-18f, 0.00576678319f, 0.0108358664f,
    0.010198079f, -9.31747402e-18f, -0.0175033181f, -0.0317660068f, -0.0284531643f,
    1.85181518e-17f, 0.0442450253f, 0.0771733386f, 0.067055491f, -2.85299239e-17f,
    -0.101548683f, -0.178708388f, -0.160004642f, 3.61741232e-17f, 0.287940558f,
    0.625431459f, 0.8970676f, 1.00107877f, 0.8970676f, 0.625431459f, 0.287940558f,
    3.61741232e-17f, -0.160004642f, -0.178708388f, -0.101548683f, -2.85299239e-17f,
    0.067055491f, 0.0771733386f, 0.0442450253f, 1.85181518e-17f, -0.0284531643f,
    -0.0317660068f, -0.0175033181f, -9.31747402e-18f, 0.010198079f, 0.0108358664f,
    0.00576678319f, 3.84904063e-18f, -0.00363442646f, -0.00463495665f,
    0.0f, 0.0f, 0.0f
};

__device__ __forceinline__ void fma4(v4f& a, float w, const v4f& v) {
    a.x = fmaf(w, v.x, a.x);
    a.y = fmaf(w, v.y, a.y);
    a.z = fmaf(w, v.z, a.z);
    a.w = fmaf(w, v.w, a.w);
}

// One block = 64-wide x 128-tall output tile of one (b,c) image.
//   H-phase: input ROWS direct from global (contiguous, halo 43x27 ~ 4.5 KB,
//            L1/L2-hot) -> horizontal polyphase -> tmp[43][64] in LDS.
//   V-phase: each thread computes TWO vertically-adjacent 4x4 patches with a
//            single sliding window: 13 b128 LDS reads for 32 outputs (vs 24).
// Per axis: out o -> phase p = o&3, m = o>>2; input i = m - 5 + j, j in [0,12),
// weight BASE48[4*j + 3 - p]. Halo rows 43 (=128/4+11), cols 27 (=64/4+11).
// LDS = 43*68*4 = 11.7 KB -> 8 blocks/CU (wave-capped). Grid 4096 = 2 rounds.
__launch_bounds__(256, 8)
__global__ void upfirdn4_t64x128_kernel(const float* __restrict__ x,
                                        float* __restrict__ out) {
    constexpr int H = 128, W = 128, OW = 512, OH = 512;
    constexpr int HR = 43, TS = 68;

    __shared__ float tmp[HR][TS];    // horizontal-pass result: 43 rows x 64 cols

    const int tid = threadIdx.x;
    const int bc  = blockIdx.z;              // b*8 + c
    const int OX  = blockIdx.x * 64;
    const int OY  = blockIdx.y * 128;
    const int I0x = (OX >> 2) - 5;
    const int I0y = (OY >> 2) - 5;

    const float* xb = x + (size_t)bc * (H * W);

    // ---- H-phase: 688 items = 43 input rows x 16 col-groups ----
    const bool interior = (I0x >= 0) & (I0x + 27 <= W) & (I0y >= 0) & (I0y + HR <= H);
    for (int t = tid; t < HR * 16; t += 256) {
        int row = t >> 4;
        int m   = t & 15;
        float a0 = 0.f, a1 = 0.f, a2 = 0.f, a3 = 0.f;
        if (interior) {
            const float* p = xb + (I0y + row) * W + (I0x + m);
#pragma unroll
            for (int j = 0; j < 12; ++j) {
                float v = p[j];
                a0 = fmaf(BASE48[4 * j + 3], v, a0);
                a1 = fmaf(BASE48[4 * j + 2], v, a1);
                a2 = fmaf(BASE48[4 * j + 1], v, a2);
                a3 = fmaf(BASE48[4 * j + 0], v, a3);
            }
        } else {
            int iy = I0y + row;
            bool vrow = (unsigned)iy < (unsigned)H;
            const float* p = xb + (vrow ? iy : 0) * W;
#pragma unroll
            for (int j = 0; j < 12; ++j) {
                int ix = I0x + m + j;
                bool ok = vrow && ((unsigned)ix < (unsigned)W);
                float v = ok ? p[ix] : 0.0f;
                a0 = fmaf(BASE48[4 * j + 3], v, a0);
                a1 = fmaf(BASE48[4 * j + 2], v, a1);
                a2 = fmaf(BASE48[4 * j + 1], v, a2);
                a3 = fmaf(BASE48[4 * j + 0], v, a3);
            }
        }
        v4f r4 = {a0, a1, a2, a3};
        *(v4f*)&tmp[row][m << 2] = r4;
    }
    __syncthreads();

    // ---- V-phase: thread -> (rg0 = 2*(tid>>4), oc = 4*(tid&15)) ----
    // Patch A: out rows 4*rg0..+3, needs tmp rows rg0..rg0+11.
    // Patch B: out rows 4*rg0+4..+7, needs tmp rows rg0+1..rg0+12.
    // One 13-read sliding window feeds both (j<12 -> A, j>=1 -> B).
    {
        const int oc  = (tid & 15) << 2;
        const int rg0 = (tid >> 4) << 1;
        v4f A0 = {0,0,0,0}, A1 = {0,0,0,0}, A2 = {0,0,0,0}, A3 = {0,0,0,0};
        v4f B0 = {0,0,0,0}, B1 = {0,0,0,0}, B2 = {0,0,0,0}, B3 = {0,0,0,0};
#pragma unroll
        for (int j = 0; j < 13; ++j) {
            v4f v = *(const v4f*)&tmp[rg0 + j][oc];
            if (j < 12) {
                fma4(A0, BASE48[4 * j + 3], v);
                fma4(A1, BASE48[4 * j + 2], v);
                fma4(A2, BASE48[4 * j + 1], v);
                fma4(A3, BASE48[4 * j + 0], v);
            }
            if (j >= 1) {
                int k = j - 1;
                fma4(B0, BASE48[4 * k + 3], v);
                fma4(B1, BASE48[4 * k + 2], v);
                fma4(B2, BASE48[4 * k + 1], v);
                fma4(B3, BASE48[4 * k + 0], v);
            }
        }
        size_t base = (size_t)bc * (OH * OW) + (size_t)(OY + (rg0 << 2)) * OW + (OX + oc);
        *(v4f*)&out[base]          = A0;
        *(v4f*)&out[base + OW]     = A1;
        *(v4f*)&out[base + 2 * OW] = A2;
        *(v4f*)&out[base + 3 * OW] = A3;
        *(v4f*)&out[base + 4 * OW] = B0;
        *(v4f*)&out[base + 5 * OW] = B1;
        *(v4f*)&out[base + 6 * OW] = B2;
        *(v4f*)&out[base + 7 * OW] = B3;
    }
}

extern "C" void kernel_launch(void* const* d_in, const int* in_sizes, int n_in,
                              void* d_out, int out_size, void* d_ws, size_t ws_size,
                              hipStream_t stream) {
    const float* x = (const float*)d_in[0];
    float* out = (float*)d_out;
    dim3 grid(8, 4, 128);   // 64x128 tiles over 512x512, z = B*C = 128
    dim3 block(256);
    upfirdn4_t64x128_kernel<<<grid, block, 0, stream>>>(x, out);
}

// Round 9
// 39.096 us; speedup vs baseline: 1.2680x; 1.2680x over previous
//
#include <hip/hip_runtime.h>

typedef float v4f __attribute__((ext_vector_type(4)));

// 45-tap palindromic filter, padded to 48 with zeros so every phase uses a
// uniform 12-tap loop: out phase p uses weight BASE48[4*j + 3 - p].
constexpr float BASE48[48] = {
    -0.00463495665f, -0.00363442646f, 3.84904063e-18f, 0.00576678319f, 0.0108358664f,
    0.010198079f, -9.31747402e-18f, -0.0175033181f, -0.0317660068f, -0.0284531643f,
    1.85181518e-17f, 0.0442450253f, 0.0771733386f, 0.067055491f, -2.85299239e-17f,
    -0.101548683f, -0.178708388f, -0.160004642f, 3.61741232e-17f, 0.287940558f,
    0.625431459f, 0.8970676f, 1.00107877f, 0.8970676f, 0.625431459f, 0.287940558f,
    3.61741232e-17f, -0.160004642f, -0.178708388f, -0.101548683f, -2.85299239e-17f,
    0.067055491f, 0.0771733386f, 0.0442450253f, 1.85181518e-17f, -0.0284531643f,
    -0.0317660068f, -0.0175033181f, -9.31747402e-18f, 0.010198079f, 0.0108358664f,
    0.00576678319f, 3.84904063e-18f, -0.00363442646f, -0.00463495665f,
    0.0f, 0.0f, 0.0f
};

__device__ __forceinline__ void fma4(v4f& a, float w, const v4f& v) {
    a.x = fmaf(w, v.x, a.x);
    a.y = fmaf(w, v.y, a.y);
    a.z = fmaf(w, v.z, a.z);
    a.w = fmaf(w, v.w, a.w);
}

// One block = 256-wide x 32-tall output tile of one (b,c) image.
//   H-phase: input rows direct from global (contiguous; halo 19x75) ->
//            horizontal polyphase -> tmp[19][256] in LDS.
//   V-phase: dual vertically-adjacent 4x4 patches per thread via a 13-read
//            sliding window. KEY: lanes 0..63 of a wave map to 64 consecutive
//            16B chunks of ONE output row -> every wave store instruction is
//            1024 B contiguous (vs 4x256B before).
// Halo rows 19 (=32/4+11), cols 75 (=256/4+11).
// LDS = 19*260*4 = 19760 B. launch_bounds(256,4): VGPR<=128, no spill.
__launch_bounds__(256, 4)
__global__ void upfirdn4_t256x32_kernel(const float* __restrict__ x,
                                        float* __restrict__ out) {
    constexpr int H = 128, W = 128, OW = 512, OH = 512;
    constexpr int HR = 19, TS = 260;

    __shared__ float tmp[HR][TS];    // 19 input rows x 256 out cols (stride 260)

    const int tid = threadIdx.x;
    const int bc  = blockIdx.z;              // b*8 + c
    const int OX  = blockIdx.x * 256;
    const int OY  = blockIdx.y * 32;
    const int I0x = (OX >> 2) - 5;
    const int I0y = (OY >> 2) - 5;

    const float* xb = x + (size_t)bc * (H * W);

    // ---- H-phase: 19*64 = 1216 items = (input row, 4-col output group m) ----
    // Item (row, m): reads xb[I0y+row][I0x+m .. +m+11], computes 4 out cols
    // (phases 0..3), writes v4f to tmp[row][4m]. Wave = one row, 64 m's ->
    // LDS write is 1 KB contiguous, conflict-free.
    for (int t = tid; t < HR * 64; t += 256) {
        int row = t >> 6;
        int m   = t & 63;
        int iy  = I0y + row;
        bool row_ok   = (unsigned)iy < (unsigned)H;
        bool col_safe = (I0x + m >= 0) & (I0x + m + 12 <= W);
        float a0 = 0.f, a1 = 0.f, a2 = 0.f, a3 = 0.f;
        if (row_ok & col_safe) {
            const float* p = xb + iy * W + (I0x + m);
#pragma unroll
            for (int j = 0; j < 12; ++j) {
                float v = p[j];
                a0 = fmaf(BASE48[4 * j + 3], v, a0);
                a1 = fmaf(BASE48[4 * j + 2], v, a1);
                a2 = fmaf(BASE48[4 * j + 1], v, a2);
                a3 = fmaf(BASE48[4 * j + 0], v, a3);
            }
        } else if (row_ok) {
            const float* p = xb + iy * W;
#pragma unroll
            for (int j = 0; j < 12; ++j) {
                int ix = I0x + m + j;
                float v = ((unsigned)ix < (unsigned)W) ? p[ix] : 0.0f;
                a0 = fmaf(BASE48[4 * j + 3], v, a0);
                a1 = fmaf(BASE48[4 * j + 2], v, a1);
                a2 = fmaf(BASE48[4 * j + 1], v, a2);
                a3 = fmaf(BASE48[4 * j + 0], v, a3);
            }
        }
        // row invalid -> zeros (matches zero padding)
        v4f r4 = {a0, a1, a2, a3};
        *(v4f*)&tmp[row][m << 2] = r4;
    }
    __syncthreads();

    // ---- V-phase: thread -> (rg0 = 2*(tid>>6) in {0,2,4,6}, oc = 4*(tid&63)) ----
    // Patch A: out rows 4*rg0..+3 (tmp rows rg0..rg0+11).
    // Patch B: out rows 4*rg0+4..+7 (tmp rows rg0+1..rg0+12).
    // rg0 is wave-uniform: each store instruction = 64 lanes x 16B = 1 KB
    // contiguous of one output row.
    {
        const int oc  = (tid & 63) << 2;
        const int rg0 = (tid >> 6) << 1;
        v4f A0 = {0,0,0,0}, A1 = {0,0,0,0}, A2 = {0,0,0,0}, A3 = {0,0,0,0};
        v4f B0 = {0,0,0,0}, B1 = {0,0,0,0}, B2 = {0,0,0,0}, B3 = {0,0,0,0};
#pragma unroll
        for (int j = 0; j < 13; ++j) {
            v4f v = *(const v4f*)&tmp[rg0 + j][oc];
            if (j < 12) {
                fma4(A0, BASE48[4 * j + 3], v);
                fma4(A1, BASE48[4 * j + 2], v);
                fma4(A2, BASE48[4 * j + 1], v);
                fma4(A3, BASE48[4 * j + 0], v);
            }
            if (j >= 1) {
                int k = j - 1;
                fma4(B0, BASE48[4 * k + 3], v);
                fma4(B1, BASE48[4 * k + 2], v);
                fma4(B2, BASE48[4 * k + 1], v);
                fma4(B3, BASE48[4 * k + 0], v);
            }
        }
        size_t base = (size_t)bc * (OH * OW) + (size_t)(OY + (rg0 << 2)) * OW + (OX + oc);
        *(v4f*)&out[base]          = A0;
        *(v4f*)&out[base + OW]     = A1;
        *(v4f*)&out[base + 2 * OW] = A2;
        *(v4f*)&out[base + 3 * OW] = A3;
        *(v4f*)&out[base + 4 * OW] = B0;
        *(v4f*)&out[base + 5 * OW] = B1;
        *(v4f*)&out[base + 6 * OW] = B2;
        *(v4f*)&out[base + 7 * OW] = B3;
    }
}

extern "C" void kernel_launch(void* const* d_in, const int* in_sizes, int n_in,
                              void* d_out, int out_size, void* d_ws, size_t ws_size,
                              hipStream_t stream) {
    const float* x = (const float*)d_in[0];
    float* out = (float*)d_out;
    dim3 grid(2, 16, 128);   // 256x32 tiles over 512x512, z = B*C = 128
    dim3 block(256);
    upfirdn4_t256x32_kernel<<<grid, block, 0, stream>>>(x, out);
}